// Round 5
// baseline (176.501 us; speedup 1.0000x reference)
//
#include <hip/hip_runtime.h>

// Problem constants: B=4, Nc=1024, Nf=8192, fp32 in/out.
#define B  4
#define NF 8192
#define NC 1024
#define TJ (NF / 32)         // 256 col-tiles per batch
#define FRAG_STRIDE 1152     // per tile: 64 lanes * 16B frag + 32 * 4B cy

#define NMIN (2 * B * NF)    // 65536 (rowbuf 32768 | colbuf 32768)
#define NCRS (B * NC)
#define NTOT (NMIN + NCRS)

typedef _Float16 h8  __attribute__((ext_vector_type(8)));
typedef float    f16v __attribute__((ext_vector_type(16)));

// ---------------------------------------------------------------------------
// One-pass MFMA chamfer: d(i,j) = cx_i + cy_j - 2*dot(x_i,y_j).
// dots via one mfma_f32_32x32x16_f16 per 32x32 tile, fp16 hi/lo split packed
// into K-slots: A k0..8 = [h0,h1,h2, l0,l1,l2, h0,h1,h2]
//               B k0..8 = [h0,h1,h2, h0,h1,h2, l0,l1,l2]
// => acc = hi.hi + lo.hi + hi.lo ~= fp32 dot (lo.lo ~2^-22 dropped).
// Row-mins (per rf point -> d1) exclusive per block; col-mins (per gf point
// -> d2) combined across row-band blocks via global uint atomicMin.
// ---------------------------------------------------------------------------

// Build B fragments + cy (|y|^2) for all (batch, col-tile).
__global__ __launch_bounds__(256) void k_prep(const float* __restrict__ gf,
                                              unsigned char* __restrict__ fragbuf) {
    int id = blockIdx.x * 256 + threadIdx.x;   // 65536 = 4 * 256 * 64
    int b  = id >> 14;
    int jt = (id >> 6) & (TJ - 1);
    int ln = id & 63;
    int n  = ln & 31;

    const float* y = gf + ((size_t)(b * NF) + jt * 32 + n) * 3;
    float y0 = y[0], y1 = y[1], y2 = y[2];
    _Float16 h0 = (_Float16)y0, h1 = (_Float16)y1, h2 = (_Float16)y2;
    _Float16 g0 = (_Float16)(y0 - (float)h0);
    _Float16 g1 = (_Float16)(y1 - (float)h1);
    _Float16 g2 = (_Float16)(y2 - (float)h2);

    h8 fr = {};
    if ((ln >> 5) == 0) {       // k = 0..7
        fr[0] = h0; fr[1] = h1; fr[2] = h2;
        fr[3] = h0; fr[4] = h1; fr[5] = h2;
        fr[6] = g0; fr[7] = g1;
    } else {                    // k = 8..15
        fr[0] = g2;
    }
    size_t off = (size_t)(b * TJ + jt) * FRAG_STRIDE;
    *(h8*)(fragbuf + off + ln * 16) = fr;
    if (ln < 32)
        *(float*)(fragbuf + off + 1024 + n * 4) =
            fmaf(y0, y0, fmaf(y1, y1, y2 * y2));
}

__global__ __launch_bounds__(256) void k_main(const float* __restrict__ rf,
                                              const unsigned char* __restrict__ fragbuf,
                                              unsigned* __restrict__ rowbuf,
                                              unsigned* __restrict__ colbuf) {
    __shared__ float xs[32];      // |x|^2 for the block's 32 rows
    __shared__ float rbuf[128];   // per-wave row-min partials

    int bx   = blockIdx.x;        // 1024 = 4 batches * 256 row-bands
    int b    = bx >> 8;
    int band = bx & 255;
    int t    = threadIdx.x;
    int ln   = t & 63;
    int w    = t >> 6;
    int m    = ln & 31;
    int kg   = ln >> 5;

    // ---- prologue: A fragment + cx ----
    const float* xr = rf + ((size_t)(b * NF) + band * 32 + m) * 3;
    float x0 = xr[0], x1 = xr[1], x2 = xr[2];
    float csq = fmaf(x0, x0, fmaf(x1, x1, x2 * x2));
    if (t < 32) xs[m] = csq;

    _Float16 a0 = (_Float16)x0, a1 = (_Float16)x1, a2 = (_Float16)x2;
    _Float16 e0 = (_Float16)(x0 - (float)a0);
    _Float16 e1 = (_Float16)(x1 - (float)a1);
    _Float16 e2 = (_Float16)(x2 - (float)a2);
    h8 afr = {};
    if (kg == 0) {              // k = 0..7
        afr[0] = a0; afr[1] = a1; afr[2] = a2;
        afr[3] = e0; afr[4] = e1; afr[5] = e2;
        afr[6] = a0; afr[7] = a1;
    } else {                    // k = 8..15
        afr[0] = a2;
    }
    __syncthreads();

    float cxr[16];
#pragma unroll
    for (int r = 0; r < 16; ++r) {
        int rc = 4 * kg + (r & 3) + 8 * (r >> 2);   // C/D row (m74/m101)
        cxr[r] = xs[rc];
    }

    float rmin[16];
#pragma unroll
    for (int r = 0; r < 16; ++r) rmin[r] = 3.4e38f;

    // ---- main loop: wave w owns col-tiles [w*64, w*64+64) ----
    const unsigned char* p = fragbuf +
        (size_t)(b * TJ + w * 64) * FRAG_STRIDE;
    unsigned* cb = colbuf + b * NF + w * 64 * 32 + m;

#pragma unroll 2
    for (int q = 0; q < 64; ++q) {
        h8    bfr = *(const h8*)(p + ln * 16);
        float cyv = *(const float*)(p + 1024 + m * 4);
        f16v acc = __builtin_amdgcn_mfma_f32_32x32x16_f16(afr, bfr, (f16v){}, 0, 0, 0);

        float cpart = 3.4e38f;
#pragma unroll
        for (int r = 0; r < 16; ++r) {
            float e = fmaf(-2.0f, acc[r], cyv);     // row path (+cx later)
            rmin[r] = fminf(rmin[r], e);
            float f = fmaf(-2.0f, acc[r], cxr[r]);  // col path (+cy now)
            cpart = fminf(cpart, f);
        }
        float oth = __shfl_xor(cpart, 32);
        float cmin = fminf(cpart, oth) + cyv;
        if (ln < 32)
            atomicMin(cb + q * 32, __float_as_uint(fmaxf(cmin, 0.0f)));
        p += FRAG_STRIDE;
    }

    // ---- row-min epilogue ----
#pragma unroll
    for (int off = 1; off <= 16; off <<= 1)
#pragma unroll
        for (int r = 0; r < 16; ++r)
            rmin[r] = fminf(rmin[r], __shfl_xor(rmin[r], off));
    if (m == 0) {               // lanes 0 and 32: disjoint row sets
#pragma unroll
        for (int r = 0; r < 16; ++r) {
            int rc = 4 * kg + (r & 3) + 8 * (r >> 2);
            rbuf[w * 32 + rc] = rmin[r];
        }
    }
    __syncthreads();
    if (t < 32) {
        float v = fminf(fminf(rbuf[t], rbuf[32 + t]),
                        fminf(rbuf[64 + t], rbuf[96 + t]));
        v = fmaxf(v + xs[t], 0.0f);
        rowbuf[b * NF + band * 32 + t] = __float_as_uint(v);
    }
}

__global__ __launch_bounds__(256) void k_reduce(const unsigned* __restrict__ minbuf,
                                                const float* __restrict__ rc,
                                                const float* __restrict__ gc,
                                                float* __restrict__ out) {
    float s_crs = 0.f, s_fine = 0.f;
    for (int i = blockIdx.x * 256 + threadIdx.x; i < NTOT; i += gridDim.x * 256) {
        if (i < NMIN) {
            s_fine += sqrtf(__uint_as_float(minbuf[i]));
        } else {
            int pnt = i - NMIN;
            float dx = rc[3 * pnt + 0] - gc[3 * pnt + 0];
            float dy = rc[3 * pnt + 1] - gc[3 * pnt + 1];
            float dz = rc[3 * pnt + 2] - gc[3 * pnt + 2];
            s_crs += sqrtf(fmaf(dx, dx, fmaf(dy, dy, dz * dz)));
        }
    }
#pragma unroll
    for (int off = 32; off > 0; off >>= 1) {
        s_crs  += __shfl_down(s_crs, off);
        s_fine += __shfl_down(s_fine, off);
    }
    __shared__ float red[2][4];
    int lane = threadIdx.x & 63, w = threadIdx.x >> 6;
    if (lane == 0) { red[0][w] = s_crs; red[1][w] = s_fine; }
    __syncthreads();
    if (threadIdx.x == 0) {
        float t0 = red[0][0] + red[0][1] + red[0][2] + red[0][3];
        float t1 = red[1][0] + red[1][1] + red[1][2] + red[1][3];
        atomicAdd(&out[0], t0 * (1.0f / (float)NCRS));     // loss_coarse
        atomicAdd(&out[1], t1 * (0.5f / (float)(B * NF))); // loss_fine
    }
}

extern "C" void kernel_launch(void* const* d_in, const int* in_sizes, int n_in,
                              void* d_out, int out_size, void* d_ws, size_t ws_size,
                              hipStream_t stream) {
    const float* rc = (const float*)d_in[0];  // ret_coarse [4,1024,3]
    const float* rf = (const float*)d_in[1];  // ret_fine   [4,8192,3]
    const float* gf = (const float*)d_in[2];  // gt_fine    [4,8192,3]
    const float* gc = (const float*)d_in[3];  // gt_coarse  [4,1024,3]

    unsigned*      rowbuf  = (unsigned*)d_ws;            // d1 mins [32768]
    unsigned*      colbuf  = rowbuf + B * NF;            // d2 mins [32768]
    unsigned char* fragbuf = (unsigned char*)(colbuf + B * NF);  // ~1.13 MB
    float*         out     = (float*)d_out;

    hipMemsetAsync(colbuf, 0xFF, (size_t)(B * NF) * sizeof(unsigned), stream);
    hipMemsetAsync(out, 0, 2 * sizeof(float), stream);

    k_prep<<<256, 256, 0, stream>>>(gf, fragbuf);
    k_main<<<B * 256, 256, 0, stream>>>(rf, fragbuf, rowbuf, colbuf);
    k_reduce<<<64, 256, 0, stream>>>(rowbuf, rc, gc, out);
}

// Round 6
// 95.116 us; speedup vs baseline: 1.8556x; 1.8556x over previous
//
#include <hip/hip_runtime.h>

// Problem constants: B=4, Nc=1024, Nf=8192, fp32 in/out.
#define B  4
#define NF 8192
#define NC 1024
#define TJ (NF / 32)          // 256 col-tiles per batch
#define BANDS 128             // 64-row bands per batch
#define TPW 32                // col-tiles per wave (8 waves/block)

#define NMIN (2 * B * NF)     // 65536 per-point NN sqrt-dists
#define NCRS (B * NC)
#define NTOT (NMIN + NCRS)

typedef _Float16 h8   __attribute__((ext_vector_type(8)));
typedef float    f16v __attribute__((ext_vector_type(16)));

// ---------------------------------------------------------------------------
// Two-pass rows-only MFMA chamfer. d(i,j) computed ENTIRELY inside one
// mfma_f32_32x32x16_f16 via augmented K-slots (fp16 hi/lo splits):
//   A k: [xh0 xh1 xh2 xl0 xl1 xl2 xh0 xh1 | xh2 sxh sxl 1 1 0 0 0]
//   B k: [mh0 mh1 mh2 mh0 mh1 mh2 ml0 ml1 | ml2 1 1 syh syl 0 0 0]
// with m = -2y (hi+lo), sx = |x|^2 (hi+lo), sy = |y|^2 (hi+lo):
//   acc = (hi.hi + lo.hi + hi.lo)(-2x.y) + |x|^2 + |y|^2 ~= d  (err ~2^-21)
// Each block exclusively owns 64 rows x all cols -> row-mins finalized with
// plain stores. NO atomics, NO colbuf, NO minbuf memset.
// Pass dir=0: x=ret_fine (d1); dir=1: x=gt_fine (d2).
// ---------------------------------------------------------------------------

// Build B fragments for both point sets: src 0 = gf, src 1 = rf.
__global__ __launch_bounds__(256) void k_prep(const float* __restrict__ rf,
                                              const float* __restrict__ gf,
                                              h8* __restrict__ fragbuf) {
    int id  = blockIdx.x * 256 + threadIdx.x;   // 131072 total
    int src = id >> 16;
    int rem = id & 65535;
    int b   = rem >> 14;
    int jt  = (rem >> 6) & (TJ - 1);
    int ln  = rem & 63;
    int n   = ln & 31, kg = ln >> 5;

    const float* y = (src ? rf : gf) + ((size_t)(b * NF) + jt * 32 + n) * 3;
    float y0 = y[0], y1 = y[1], y2 = y[2];
    float t0 = -2.0f * y0, t1 = -2.0f * y1, t2 = -2.0f * y2;
    _Float16 mh0 = (_Float16)t0, mh1 = (_Float16)t1, mh2 = (_Float16)t2;
    _Float16 ml0 = (_Float16)(t0 - (float)mh0);
    _Float16 ml1 = (_Float16)(t1 - (float)mh1);
    _Float16 ml2 = (_Float16)(t2 - (float)mh2);
    float sy = fmaf(y0, y0, fmaf(y1, y1, y2 * y2));
    _Float16 syh = (_Float16)sy;
    _Float16 syl = (_Float16)(sy - (float)syh);

    h8 fr = {};
    if (kg == 0) {
        fr[0] = mh0; fr[1] = mh1; fr[2] = mh2;
        fr[3] = mh0; fr[4] = mh1; fr[5] = mh2;
        fr[6] = ml0; fr[7] = ml1;
    } else {
        fr[0] = ml2; fr[1] = (_Float16)1.0f; fr[2] = (_Float16)1.0f;
        fr[3] = syh; fr[4] = syl;
    }
    fragbuf[((size_t)(src * B + b) * TJ + jt) * 64 + ln] = fr;
}

__global__ __launch_bounds__(512) void k_main(const float* __restrict__ rf,
                                              const float* __restrict__ gf,
                                              const h8* __restrict__ fragbuf,
                                              float* __restrict__ rowbuf) {
    __shared__ float rbuf[8][64];

    int bx   = blockIdx.x;      // 1024 = 2 dirs * 4 batches * 128 bands
    int dir  = bx >> 9;
    int rem  = bx & 511;
    int b    = rem >> 7;
    int band = rem & 127;
    int t  = threadIdx.x;
    int ln = t & 63, w = t >> 6, m = ln & 31, kg = ln >> 5;

    // ---- A fragments for the block's 64 rows (2 per wave, wave-redundant) --
    const float* xp = dir ? gf : rf;
    h8 afr[2];
#pragma unroll
    for (int f = 0; f < 2; ++f) {
        const float* xr = xp + ((size_t)(b * NF) + band * 64 + f * 32 + m) * 3;
        float x0 = xr[0], x1 = xr[1], x2 = xr[2];
        _Float16 h0 = (_Float16)x0, h1 = (_Float16)x1, h2 = (_Float16)x2;
        _Float16 l0 = (_Float16)(x0 - (float)h0);
        _Float16 l1 = (_Float16)(x1 - (float)h1);
        _Float16 l2 = (_Float16)(x2 - (float)h2);
        float sx = fmaf(x0, x0, fmaf(x1, x1, x2 * x2));
        _Float16 sh = (_Float16)sx;
        _Float16 sl = (_Float16)(sx - (float)sh);
        h8 fr = {};
        if (kg == 0) {
            fr[0] = h0; fr[1] = h1; fr[2] = h2;
            fr[3] = l0; fr[4] = l1; fr[5] = l2;
            fr[6] = h0; fr[7] = h1;
        } else {
            fr[0] = h2; fr[1] = sh; fr[2] = sl;
            fr[3] = (_Float16)1.0f; fr[4] = (_Float16)1.0f;
        }
        afr[f] = fr;
    }

    float rmin0[16], rmin1[16];
#pragma unroll
    for (int r = 0; r < 16; ++r) { rmin0[r] = 3.4e38f; rmin1[r] = 3.4e38f; }

    // ---- main loop: wave w owns col-tiles [w*TPW, (w+1)*TPW) ----
    // Per iteration: 1 coalesced 16B load + 2 MFMA + 32 v_min_f32.
    const h8* p = fragbuf + ((size_t)(dir * B + b) * TJ + w * TPW) * 64 + ln;
#pragma unroll 2
    for (int q = 0; q < TPW; ++q) {
        h8 bfr = p[(size_t)q * 64];
        f16v acc0 = __builtin_amdgcn_mfma_f32_32x32x16_f16(afr[0], bfr, (f16v){}, 0, 0, 0);
        f16v acc1 = __builtin_amdgcn_mfma_f32_32x32x16_f16(afr[1], bfr, (f16v){}, 0, 0, 0);
#pragma unroll
        for (int r = 0; r < 16; ++r) rmin0[r] = fminf(rmin0[r], acc0[r]);
#pragma unroll
        for (int r = 0; r < 16; ++r) rmin1[r] = fminf(rmin1[r], acc1[r]);
    }

    // ---- epilogue: min over cols (lanes within half-wave), then waves ----
#pragma unroll
    for (int off = 1; off <= 16; off <<= 1) {
#pragma unroll
        for (int r = 0; r < 16; ++r) {
            rmin0[r] = fminf(rmin0[r], __shfl_xor(rmin0[r], off));
            rmin1[r] = fminf(rmin1[r], __shfl_xor(rmin1[r], off));
        }
    }
    if (m == 0) {   // lanes 0 (kg=0) and 32 (kg=1): disjoint row sets
#pragma unroll
        for (int r = 0; r < 16; ++r) {
            int row = 4 * kg + (r & 3) + 8 * (r >> 2);   // C/D map (m74/m101)
            rbuf[w][row]      = rmin0[r];
            rbuf[w][32 + row] = rmin1[r];
        }
    }
    __syncthreads();
    if (t < 64) {
        float v = rbuf[0][t];
#pragma unroll
        for (int ww = 1; ww < 8; ++ww) v = fminf(v, rbuf[ww][t]);
        rowbuf[(size_t)dir * (B * NF) + b * NF + band * 64 + t] =
            sqrtf(fmaxf(v, 0.0f));
    }
}

__global__ __launch_bounds__(256) void k_reduce(const float* __restrict__ rowbuf,
                                                const float* __restrict__ rc,
                                                const float* __restrict__ gc,
                                                float* __restrict__ out) {
    float s_crs = 0.f, s_fine = 0.f;
    for (int i = blockIdx.x * 256 + threadIdx.x; i < NTOT; i += gridDim.x * 256) {
        if (i < NMIN) {
            s_fine += rowbuf[i];                     // already sqrt'd
        } else {
            int pnt = i - NMIN;
            float dx = rc[3 * pnt + 0] - gc[3 * pnt + 0];
            float dy = rc[3 * pnt + 1] - gc[3 * pnt + 1];
            float dz = rc[3 * pnt + 2] - gc[3 * pnt + 2];
            s_crs += sqrtf(fmaf(dx, dx, fmaf(dy, dy, dz * dz)));
        }
    }
#pragma unroll
    for (int off = 32; off > 0; off >>= 1) {
        s_crs  += __shfl_down(s_crs, off);
        s_fine += __shfl_down(s_fine, off);
    }
    __shared__ float red[2][4];
    int lane = threadIdx.x & 63, w = threadIdx.x >> 6;
    if (lane == 0) { red[0][w] = s_crs; red[1][w] = s_fine; }
    __syncthreads();
    if (threadIdx.x == 0) {
        float t0 = red[0][0] + red[0][1] + red[0][2] + red[0][3];
        float t1 = red[1][0] + red[1][1] + red[1][2] + red[1][3];
        atomicAdd(&out[0], t0 * (1.0f / (float)NCRS));     // loss_coarse
        atomicAdd(&out[1], t1 * (0.5f / (float)(B * NF))); // loss_fine
    }
}

extern "C" void kernel_launch(void* const* d_in, const int* in_sizes, int n_in,
                              void* d_out, int out_size, void* d_ws, size_t ws_size,
                              hipStream_t stream) {
    const float* rc = (const float*)d_in[0];  // ret_coarse [4,1024,3]
    const float* rf = (const float*)d_in[1];  // ret_fine   [4,8192,3]
    const float* gf = (const float*)d_in[2];  // gt_fine    [4,8192,3]
    const float* gc = (const float*)d_in[3];  // gt_coarse  [4,1024,3]

    float* rowbuf  = (float*)d_ws;                           // 256 KB
    h8*    fragbuf = (h8*)((char*)d_ws + (size_t)NMIN * 4);  // 2 MB
    float* out     = (float*)d_out;

    hipMemsetAsync(out, 0, 2 * sizeof(float), stream);
    k_prep<<<512, 256, 0, stream>>>(rf, gf, fragbuf);
    k_main<<<2 * B * BANDS, 512, 0, stream>>>(rf, gf, fragbuf, rowbuf);
    k_reduce<<<64, 256, 0, stream>>>(rowbuf, rc, gc, out);
}

// Round 7
// 94.376 us; speedup vs baseline: 1.8702x; 1.0078x over previous
//
#include <hip/hip_runtime.h>

// Problem constants: B=4, Nc=1024, Nf=8192, fp32 in/out.
#define B  4
#define NF 8192
#define NC 1024
#define TJ (NF / 32)          // 256 col-tiles per batch
#define BANDS 128             // 64-row bands per batch
#define TPW 32                // col-tiles per wave (8 waves/block)

#define NMIN (2 * B * NF)     // 65536 per-point NN sqrt-dists
#define NCRS (B * NC)
#define NTOT (NMIN + NCRS)

typedef _Float16 h8   __attribute__((ext_vector_type(8)));
typedef float    f16v __attribute__((ext_vector_type(16)));

// ---------------------------------------------------------------------------
// Two-pass rows-only MFMA chamfer (validated round 6, absmax 0.0).
// d(i,j) computed ENTIRELY inside one mfma_f32_32x32x16_f16 via augmented
// K-slots (fp16 hi/lo splits):
//   A k: [xh0 xh1 xh2 xl0 xl1 xl2 xh0 xh1 | xh2 sxh sxl 1 1 0 0 0]
//   B k: [mh0 mh1 mh2 mh0 mh1 mh2 ml0 ml1 | ml2 1 1 syh syl 0 0 0]
// with m = -2y (hi+lo), s = |.|^2 (hi+lo):  acc[r] ~= d  (err ~2^-21).
// Round 7: col-tile PAIRS folded with v_min3_f32 (halves hot-loop VALU) +
// unconditional next-pair prefetch (fragbuf padded) to hide L2 latency.
// ---------------------------------------------------------------------------

// Build B fragments for both point sets: src 0 = gf, src 1 = rf.
__global__ __launch_bounds__(256) void k_prep(const float* __restrict__ rf,
                                              const float* __restrict__ gf,
                                              h8* __restrict__ fragbuf) {
    int id  = blockIdx.x * 256 + threadIdx.x;   // 131072 total
    int src = id >> 16;
    int rem = id & 65535;
    int b   = rem >> 14;
    int jt  = (rem >> 6) & (TJ - 1);
    int ln  = rem & 63;
    int n   = ln & 31, kg = ln >> 5;

    const float* y = (src ? rf : gf) + ((size_t)(b * NF) + jt * 32 + n) * 3;
    float y0 = y[0], y1 = y[1], y2 = y[2];
    float t0 = -2.0f * y0, t1 = -2.0f * y1, t2 = -2.0f * y2;
    _Float16 mh0 = (_Float16)t0, mh1 = (_Float16)t1, mh2 = (_Float16)t2;
    _Float16 ml0 = (_Float16)(t0 - (float)mh0);
    _Float16 ml1 = (_Float16)(t1 - (float)mh1);
    _Float16 ml2 = (_Float16)(t2 - (float)mh2);
    float sy = fmaf(y0, y0, fmaf(y1, y1, y2 * y2));
    _Float16 syh = (_Float16)sy;
    _Float16 syl = (_Float16)(sy - (float)syh);

    h8 fr = {};
    if (kg == 0) {
        fr[0] = mh0; fr[1] = mh1; fr[2] = mh2;
        fr[3] = mh0; fr[4] = mh1; fr[5] = mh2;
        fr[6] = ml0; fr[7] = ml1;
    } else {
        fr[0] = ml2; fr[1] = (_Float16)1.0f; fr[2] = (_Float16)1.0f;
        fr[3] = syh; fr[4] = syl;
    }
    fragbuf[((size_t)(src * B + b) * TJ + jt) * 64 + ln] = fr;
}

__global__ __launch_bounds__(512) void k_main(const float* __restrict__ rf,
                                              const float* __restrict__ gf,
                                              const h8* __restrict__ fragbuf,
                                              float* __restrict__ rowbuf) {
    __shared__ float rbuf[8][64];

    int bx   = blockIdx.x;      // 1024 = 2 dirs * 4 batches * 128 bands
    int dir  = bx >> 9;
    int rem  = bx & 511;
    int b    = rem >> 7;
    int band = rem & 127;
    int t  = threadIdx.x;
    int ln = t & 63, w = t >> 6, m = ln & 31, kg = ln >> 5;

    // ---- A fragments for the block's 64 rows (2 per wave, wave-redundant) --
    const float* xp = dir ? gf : rf;
    h8 afr[2];
#pragma unroll
    for (int f = 0; f < 2; ++f) {
        const float* xr = xp + ((size_t)(b * NF) + band * 64 + f * 32 + m) * 3;
        float x0 = xr[0], x1 = xr[1], x2 = xr[2];
        _Float16 h0 = (_Float16)x0, h1 = (_Float16)x1, h2 = (_Float16)x2;
        _Float16 l0 = (_Float16)(x0 - (float)h0);
        _Float16 l1 = (_Float16)(x1 - (float)h1);
        _Float16 l2 = (_Float16)(x2 - (float)h2);
        float sx = fmaf(x0, x0, fmaf(x1, x1, x2 * x2));
        _Float16 sh = (_Float16)sx;
        _Float16 sl = (_Float16)(sx - (float)sh);
        h8 fr = {};
        if (kg == 0) {
            fr[0] = h0; fr[1] = h1; fr[2] = h2;
            fr[3] = l0; fr[4] = l1; fr[5] = l2;
            fr[6] = h0; fr[7] = h1;
        } else {
            fr[0] = h2; fr[1] = sh; fr[2] = sl;
            fr[3] = (_Float16)1.0f; fr[4] = (_Float16)1.0f;
        }
        afr[f] = fr;
    }

    float rmin0[16], rmin1[16];
#pragma unroll
    for (int r = 0; r < 16; ++r) { rmin0[r] = 3.4e38f; rmin1[r] = 3.4e38f; }

    // ---- main loop: wave w owns col-tile pairs; per pair:
    //      2 loads (prefetched) + 4 MFMA + 32 v_min3_f32.
    const h8* p = fragbuf + ((size_t)(dir * B + b) * TJ + w * TPW) * 64 + ln;
    h8 b0 = p[0];
    h8 b1 = p[64];
#pragma unroll 2
    for (int q = 0; q < TPW / 2; ++q) {
        // Unconditional prefetch of the next pair (fragbuf tail-padded 2KB).
        h8 n0 = p[(2 * q + 2) * 64];
        h8 n1 = p[(2 * q + 3) * 64];
        f16v c00 = __builtin_amdgcn_mfma_f32_32x32x16_f16(afr[0], b0, (f16v){}, 0, 0, 0);
        f16v c01 = __builtin_amdgcn_mfma_f32_32x32x16_f16(afr[0], b1, (f16v){}, 0, 0, 0);
#pragma unroll
        for (int r = 0; r < 16; ++r)
            rmin0[r] = fminf(fminf(c00[r], c01[r]), rmin0[r]);   // v_min3_f32
        f16v c10 = __builtin_amdgcn_mfma_f32_32x32x16_f16(afr[1], b0, (f16v){}, 0, 0, 0);
        f16v c11 = __builtin_amdgcn_mfma_f32_32x32x16_f16(afr[1], b1, (f16v){}, 0, 0, 0);
#pragma unroll
        for (int r = 0; r < 16; ++r)
            rmin1[r] = fminf(fminf(c10[r], c11[r]), rmin1[r]);
        b0 = n0;
        b1 = n1;
    }

    // ---- epilogue: min over cols (lanes within half-wave), then waves ----
#pragma unroll
    for (int off = 1; off <= 16; off <<= 1) {
#pragma unroll
        for (int r = 0; r < 16; ++r) {
            rmin0[r] = fminf(rmin0[r], __shfl_xor(rmin0[r], off));
            rmin1[r] = fminf(rmin1[r], __shfl_xor(rmin1[r], off));
        }
    }
    if (m == 0) {   // lanes 0 (kg=0) and 32 (kg=1): disjoint row sets
#pragma unroll
        for (int r = 0; r < 16; ++r) {
            int row = 4 * kg + (r & 3) + 8 * (r >> 2);   // C/D map (m74/m101)
            rbuf[w][row]      = rmin0[r];
            rbuf[w][32 + row] = rmin1[r];
        }
    }
    __syncthreads();
    if (t < 64) {
        float v = rbuf[0][t];
#pragma unroll
        for (int ww = 1; ww < 8; ++ww) v = fminf(v, rbuf[ww][t]);
        rowbuf[(size_t)dir * (B * NF) + b * NF + band * 64 + t] =
            sqrtf(fmaxf(v, 0.0f));
    }
}

__global__ __launch_bounds__(256) void k_reduce(const float* __restrict__ rowbuf,
                                                const float* __restrict__ rc,
                                                const float* __restrict__ gc,
                                                float* __restrict__ out) {
    float s_crs = 0.f, s_fine = 0.f;
    for (int i = blockIdx.x * 256 + threadIdx.x; i < NTOT; i += gridDim.x * 256) {
        if (i < NMIN) {
            s_fine += rowbuf[i];                     // already sqrt'd
        } else {
            int pnt = i - NMIN;
            float dx = rc[3 * pnt + 0] - gc[3 * pnt + 0];
            float dy = rc[3 * pnt + 1] - gc[3 * pnt + 1];
            float dz = rc[3 * pnt + 2] - gc[3 * pnt + 2];
            s_crs += sqrtf(fmaf(dx, dx, fmaf(dy, dy, dz * dz)));
        }
    }
#pragma unroll
    for (int off = 32; off > 0; off >>= 1) {
        s_crs  += __shfl_down(s_crs, off);
        s_fine += __shfl_down(s_fine, off);
    }
    __shared__ float red[2][4];
    int lane = threadIdx.x & 63, w = threadIdx.x >> 6;
    if (lane == 0) { red[0][w] = s_crs; red[1][w] = s_fine; }
    __syncthreads();
    if (threadIdx.x == 0) {
        float t0 = red[0][0] + red[0][1] + red[0][2] + red[0][3];
        float t1 = red[1][0] + red[1][1] + red[1][2] + red[1][3];
        atomicAdd(&out[0], t0 * (1.0f / (float)NCRS));     // loss_coarse
        atomicAdd(&out[1], t1 * (0.5f / (float)(B * NF))); // loss_fine
    }
}

extern "C" void kernel_launch(void* const* d_in, const int* in_sizes, int n_in,
                              void* d_out, int out_size, void* d_ws, size_t ws_size,
                              hipStream_t stream) {
    const float* rc = (const float*)d_in[0];  // ret_coarse [4,1024,3]
    const float* rf = (const float*)d_in[1];  // ret_fine   [4,8192,3]
    const float* gf = (const float*)d_in[2];  // gt_fine    [4,8192,3]
    const float* gc = (const float*)d_in[3];  // gt_coarse  [4,1024,3]

    float* rowbuf  = (float*)d_ws;                           // 256 KB
    h8*    fragbuf = (h8*)((char*)d_ws + (size_t)NMIN * 4);  // 2 MB (+2KB pad
    float* out     = (float*)d_out;                          //  for prefetch)

    hipMemsetAsync(out, 0, 2 * sizeof(float), stream);
    k_prep<<<512, 256, 0, stream>>>(rf, gf, fragbuf);
    k_main<<<2 * B * BANDS, 512, 0, stream>>>(rf, gf, fragbuf, rowbuf);
    k_reduce<<<64, 256, 0, stream>>>(rowbuf, rc, gc, out);
}